// Round 1
// baseline (83.937 us; speedup 1.0000x reference)
//
#include <hip/hip_runtime.h>
#include <hip/hip_bf16.h>

typedef __bf16 bf16x8 __attribute__((ext_vector_type(8)));
typedef float  f32x4  __attribute__((ext_vector_type(4)));

constexpr int B = 8, N = 4096, T = 128, D = 32;
constexpr float GAMMA = 0.001f;
constexpr float LOG2E = 1.4426950408889634f;
constexpr float K2 = -GAMMA * LOG2E;   // coeff on (sq1+sq2) and dist
constexpr float M2 = -2.0f * K2;       // coeff on dot  (= +2*gamma*log2e)

// ---------------------------------------------------------------------------
// Kernel 1: p1 = x@W1+b1, p2 = x@W2+b2  -> bf16; s = K2 * ||p||^2 per row.
// One wave per row (B*N rows). Lanes 0-31 -> mat1 cols, 32-63 -> mat2 cols.
// ---------------------------------------------------------------------------
__global__ __launch_bounds__(256) void proj_kernel(
    const float* __restrict__ x,  const float* __restrict__ W1,
    const float* __restrict__ b1, const float* __restrict__ W2,
    const float* __restrict__ b2,
    __bf16* __restrict__ p1b, __bf16* __restrict__ p2b,
    float* __restrict__ s1, float* __restrict__ s2) {
  __shared__ float Xs[4][T];
  const int lane = threadIdx.x & 63;
  const int wid  = threadIdx.x >> 6;
  const int row  = (blockIdx.x << 2) + wid;          // 0 .. B*N-1
  const float* xr = x + (size_t)row * T;
  Xs[wid][lane]      = xr[lane];
  Xs[wid][64 + lane] = xr[64 + lane];
  __syncthreads();

  const int  d   = lane & 31;
  const bool is2 = lane >= 32;
  const float* W = is2 ? W2 : W1;
  float acc = is2 ? b2[d] : b1[d];
  #pragma unroll
  for (int t4 = 0; t4 < T / 4; ++t4) {
    const f32x4 xv = *reinterpret_cast<const f32x4*>(&Xs[wid][t4 * 4]);
    #pragma unroll
    for (int u = 0; u < 4; ++u)
      acc = fmaf(xv[u], W[(t4 * 4 + u) * D + d], acc);
  }

  // squared norm over the 32 lanes of each half-wave
  float sq = acc * acc;
  #pragma unroll
  for (int m = 1; m < 32; m <<= 1) sq += __shfl_xor(sq, m, 64);

  if (!is2) {
    p1b[(size_t)row * D + d] = (__bf16)acc;
    if (d == 0) s1[row] = K2 * sq;
  } else {
    p2b[(size_t)row * D + d] = (__bf16)acc;
    if (d == 0) s2[row] = K2 * sq;
  }
}

// ---------------------------------------------------------------------------
// Kernel 2: fused  exp(-gamma * max(sq1+sq2-2*p1.p2, 0)) mean over batch.
// Wave computes a 32x64 output tile; block = 4 waves = 128x64 tile.
// mfma_f32_16x16x32_bf16: A/B frag = contiguous 8 bf16 at
//   row/col = lane&15, kbase = (lane>>4)*8; C/D: col=lane&15, row=(lane>>4)*4+r
// ---------------------------------------------------------------------------
__global__ __launch_bounds__(256) void fused_kernel(
    const __bf16* __restrict__ p1b, const __bf16* __restrict__ p2b,
    const float* __restrict__ s1,   const float* __restrict__ s2,
    float* __restrict__ out) {
  const int lane = threadIdx.x & 63;
  const int wid  = threadIdx.x >> 6;
  const int j0 = blockIdx.x * 64;               // col base
  const int i0 = blockIdx.y * 128 + wid * 32;   // row base (per wave)
  const int lr = lane & 15;
  const int lk = lane >> 4;

  f32x4 acc[2][4];
  #pragma unroll
  for (int a = 0; a < 2; ++a)
    #pragma unroll
    for (int c = 0; c < 4; ++c)
      acc[a][c] = f32x4{0.f, 0.f, 0.f, 0.f};

  for (int b = 0; b < B; ++b) {
    const int rb0 = b * N;

    bf16x8 afr[2];
    #pragma unroll
    for (int a = 0; a < 2; ++a)
      afr[a] = *reinterpret_cast<const bf16x8*>(
          p1b + (size_t)(rb0 + i0 + a * 16 + lr) * D + lk * 8);

    bf16x8 bfr[4];
    #pragma unroll
    for (int c = 0; c < 4; ++c)
      bfr[c] = *reinterpret_cast<const bf16x8*>(
          p2b + (size_t)(rb0 + j0 + c * 16 + lr) * D + lk * 8);

    f32x4 s1v[2];
    #pragma unroll
    for (int a = 0; a < 2; ++a)
      s1v[a] = *reinterpret_cast<const f32x4*>(s1 + rb0 + i0 + a * 16 + lk * 4);

    float s2v[4];
    #pragma unroll
    for (int c = 0; c < 4; ++c)
      s2v[c] = s2[rb0 + j0 + c * 16 + lr];

    #pragma unroll
    for (int a = 0; a < 2; ++a) {
      #pragma unroll
      for (int c = 0; c < 4; ++c) {
        f32x4 dot = __builtin_amdgcn_mfma_f32_16x16x32_bf16(
            afr[a], bfr[c], f32x4{0.f, 0.f, 0.f, 0.f}, 0, 0, 0);
        #pragma unroll
        for (int r = 0; r < 4; ++r) {
          float t = fmaf(M2, dot[r], s1v[a][r] + s2v[c]);
          t = fminf(t, 0.0f);                 // == max(dist,0) after exp
          acc[a][c][r] += exp2f(t);
        }
      }
    }
  }

  #pragma unroll
  for (int a = 0; a < 2; ++a) {
    #pragma unroll
    for (int c = 0; c < 4; ++c) {
      #pragma unroll
      for (int r = 0; r < 4; ++r) {
        const int row = i0 + a * 16 + lk * 4 + r;
        const int col = j0 + c * 16 + lr;
        const float v = acc[a][c][r] * 0.125f;
        out[(size_t)row * N + col] = (row == col) ? 0.1f : v;
      }
    }
  }
}

extern "C" void kernel_launch(void* const* d_in, const int* in_sizes, int n_in,
                              void* d_out, int out_size, void* d_ws, size_t ws_size,
                              hipStream_t stream) {
  (void)in_sizes; (void)n_in; (void)out_size; (void)ws_size;
  const float* x  = (const float*)d_in[0];
  const float* W1 = (const float*)d_in[1];
  const float* b1 = (const float*)d_in[2];
  const float* W2 = (const float*)d_in[3];
  const float* b2 = (const float*)d_in[4];
  float* out = (float*)d_out;

  char* ws = (char*)d_ws;
  const size_t pbytes = (size_t)B * N * D * sizeof(__bf16);  // 2 MB each
  __bf16* p1b = (__bf16*)ws;
  __bf16* p2b = (__bf16*)(ws + pbytes);
  float*  s1  = (float*)(ws + 2 * pbytes);
  float*  s2  = (float*)(ws + 2 * pbytes + (size_t)B * N * sizeof(float));

  proj_kernel<<<(B * N) / 4, 256, 0, stream>>>(x, W1, b1, W2, b2, p1b, p2b, s1, s2);

  dim3 grid(N / 64, N / 128);
  fused_kernel<<<grid, 256, 0, stream>>>(p1b, p2b, s1, s2, out);
}

// Round 2
// 46.741 us; speedup vs baseline: 1.7958x; 1.7958x over previous
//
#include <hip/hip_runtime.h>
#include <hip/hip_bf16.h>

typedef __bf16 bf16x8 __attribute__((ext_vector_type(8)));
typedef float  f32x4  __attribute__((ext_vector_type(4)));

constexpr int B = 8, N = 4096, T = 128, D = 32;
constexpr float GAMMA = 0.001f;
constexpr float LOG2E = 1.4426950408889634f;
constexpr float K2 = -GAMMA * LOG2E;   // coeff on sq1 / sq2 (log2 domain)
constexpr float M2 = -2.0f * K2;       // coeff on dot

__device__ __forceinline__ float exp2_fast(float t) {
#if __has_builtin(__builtin_amdgcn_exp2f)
  return __builtin_amdgcn_exp2f(t);
#else
  return exp2f(t);
#endif
}

// ---------------------------------------------------------------------------
// Kernel 1 (MFMA proj): p1' = M2*(x@W1+b1) bf16, p2 = x@W2+b2 bf16,
// s1 = K2*||p1||^2, e2 = 0.125*exp2(K2*||p2||^2).
// Block = 256 thr = 4 waves; wave handles 16 rows. Cols 0..63 = [W1|W2].
// A frag: row = lane&15, k = (lane>>4)*8 + j (proven layout from round 1).
// B frag: "col" = lane&15, k = (lane>>4)*8 + j. C/D: col=lane&15,
// row=(lane>>4)*4+r  -> bias & norms fold naturally.
// ---------------------------------------------------------------------------
__global__ __launch_bounds__(256, 2) void proj_mfma(
    const float* __restrict__ x,  const float* __restrict__ W1,
    const float* __restrict__ b1, const float* __restrict__ W2,
    const float* __restrict__ b2,
    __bf16* __restrict__ p1b, __bf16* __restrict__ p2b,
    float* __restrict__ s1, float* __restrict__ e2) {
  const int lane = threadIdx.x & 63;
  const int wid  = threadIdx.x >> 6;
  const int lr   = lane & 15;
  const int lk   = lane >> 4;
  const int r0   = blockIdx.x * 64 + wid * 16;   // 0 .. B*N-1

  // W fragments (one-time per wave; W is 32 KB, L2-hot after first blocks)
  bf16x8 wf[4][4];
  #pragma unroll
  for (int c = 0; c < 4; ++c) {
    const float* Wp = (c < 2) ? W1 : W2;
    const int cc = (c * 16 + lr) & 31;
    #pragma unroll
    for (int s = 0; s < 4; ++s)
      #pragma unroll
      for (int j = 0; j < 8; ++j)
        wf[c][s][j] = (__bf16)Wp[(s * 32 + lk * 8 + j) * D + cc];
  }

  // A fragments from x (f32 -> bf16)
  bf16x8 af[4];
  const float* xr = x + (size_t)(r0 + lr) * T;
  #pragma unroll
  for (int s = 0; s < 4; ++s) {
    const int t0 = s * 32 + lk * 8;
    const f32x4 v0 = *reinterpret_cast<const f32x4*>(xr + t0);
    const f32x4 v1 = *reinterpret_cast<const f32x4*>(xr + t0 + 4);
    #pragma unroll
    for (int j = 0; j < 4; ++j) {
      af[s][j]     = (__bf16)v0[j];
      af[s][4 + j] = (__bf16)v1[j];
    }
  }

  // MFMA with bias in C-in
  f32x4 pv[4];
  #pragma unroll
  for (int c = 0; c < 4; ++c) {
    const float* bp = (c < 2) ? b1 : b2;
    const float bv = bp[(c * 16 + lr) & 31];
    f32x4 accv = {bv, bv, bv, bv};
    #pragma unroll
    for (int s = 0; s < 4; ++s)
      accv = __builtin_amdgcn_mfma_f32_16x16x32_bf16(af[s], wf[c][s], accv, 0, 0, 0);
    pv[c] = accv;
  }

  // store p (p1 pre-scaled by M2)
  #pragma unroll
  for (int c = 0; c < 2; ++c)
    #pragma unroll
    for (int r = 0; r < 4; ++r)
      p1b[(size_t)(r0 + lk * 4 + r) * D + c * 16 + lr] = (__bf16)(M2 * pv[c][r]);
  #pragma unroll
  for (int c = 2; c < 4; ++c)
    #pragma unroll
    for (int r = 0; r < 4; ++r)
      p2b[(size_t)(r0 + lk * 4 + r) * D + (c - 2) * 16 + lr] = (__bf16)pv[c][r];

  // row squared norms: reduce over the 16 col-lanes
  float q1[4], q2[4];
  #pragma unroll
  for (int r = 0; r < 4; ++r) {
    q1[r] = fmaf(pv[0][r], pv[0][r], pv[1][r] * pv[1][r]);
    q2[r] = fmaf(pv[2][r], pv[2][r], pv[3][r] * pv[3][r]);
  }
  #pragma unroll
  for (int m = 1; m < 16; m <<= 1)
    #pragma unroll
    for (int r = 0; r < 4; ++r) {
      q1[r] += __shfl_xor(q1[r], m, 64);
      q2[r] += __shfl_xor(q2[r], m, 64);
    }
  if (lr == 0) {
    #pragma unroll
    for (int r = 0; r < 4; ++r) {
      const int row = r0 + lk * 4 + r;
      s1[row] = K2 * q1[r];
      e2[row] = 0.125f * exp2_fast(K2 * q2[r]);
    }
  }
}

// ---------------------------------------------------------------------------
// Kernel 2: acc(i,j) = sum_b e2[b,j] * exp2( M2*dot + K2*sq1 ), where
// M2*dot + K2*sq1 comes straight out of the MFMA (p1 pre-scaled, s1 as C-in).
// Wave computes 32x64 tile; block = 4 waves = 128x64.
// ---------------------------------------------------------------------------
__global__ __launch_bounds__(256, 4) void fused_kernel(
    const __bf16* __restrict__ p1b, const __bf16* __restrict__ p2b,
    const float* __restrict__ s1,   const float* __restrict__ e2,
    float* __restrict__ out) {
  const int lane = threadIdx.x & 63;
  const int wid  = threadIdx.x >> 6;
  const int j0 = blockIdx.x * 64;
  const int i0 = blockIdx.y * 128 + wid * 32;
  const int lr = lane & 15;
  const int lk = lane >> 4;

  f32x4 acc[2][4];
  #pragma unroll
  for (int a = 0; a < 2; ++a)
    #pragma unroll
    for (int c = 0; c < 4; ++c)
      acc[a][c] = f32x4{0.f, 0.f, 0.f, 0.f};

  for (int b = 0; b < B; ++b) {
    const int rb0 = b * N;

    bf16x8 afr[2];
    #pragma unroll
    for (int a = 0; a < 2; ++a)
      afr[a] = *reinterpret_cast<const bf16x8*>(
          p1b + (size_t)(rb0 + i0 + a * 16 + lr) * D + lk * 8);

    bf16x8 bfr[4];
    #pragma unroll
    for (int c = 0; c < 4; ++c)
      bfr[c] = *reinterpret_cast<const bf16x8*>(
          p2b + (size_t)(rb0 + j0 + c * 16 + lr) * D + lk * 8);

    f32x4 s1v[2];
    #pragma unroll
    for (int a = 0; a < 2; ++a)
      s1v[a] = *reinterpret_cast<const f32x4*>(s1 + rb0 + i0 + a * 16 + lk * 4);

    float e2v[4];
    #pragma unroll
    for (int c = 0; c < 4; ++c)
      e2v[c] = e2[rb0 + j0 + c * 16 + lr];

    #pragma unroll
    for (int a = 0; a < 2; ++a) {
      #pragma unroll
      for (int c = 0; c < 4; ++c) {
        f32x4 t = __builtin_amdgcn_mfma_f32_16x16x32_bf16(
            afr[a], bfr[c], s1v[a], 0, 0, 0);
        #pragma unroll
        for (int r = 0; r < 4; ++r)
          acc[a][c][r] = fmaf(e2v[c], exp2_fast(t[r]), acc[a][c][r]);
      }
    }
  }

  const bool hasdiag = (i0 < j0 + 64) && (j0 < i0 + 32);
  #pragma unroll
  for (int a = 0; a < 2; ++a) {
    #pragma unroll
    for (int c = 0; c < 4; ++c) {
      #pragma unroll
      for (int r = 0; r < 4; ++r) {
        const int row = i0 + a * 16 + lk * 4 + r;
        const int col = j0 + c * 16 + lr;
        float v = acc[a][c][r];
        if (hasdiag && row == col) v = 0.1f;
        out[(size_t)row * N + col] = v;
      }
    }
  }
}

extern "C" void kernel_launch(void* const* d_in, const int* in_sizes, int n_in,
                              void* d_out, int out_size, void* d_ws, size_t ws_size,
                              hipStream_t stream) {
  (void)in_sizes; (void)n_in; (void)out_size; (void)ws_size;
  const float* x  = (const float*)d_in[0];
  const float* W1 = (const float*)d_in[1];
  const float* b1 = (const float*)d_in[2];
  const float* W2 = (const float*)d_in[3];
  const float* b2 = (const float*)d_in[4];
  float* out = (float*)d_out;

  char* ws = (char*)d_ws;
  const size_t pbytes = (size_t)B * N * D * sizeof(__bf16);  // 2 MB each
  __bf16* p1b = (__bf16*)ws;
  __bf16* p2b = (__bf16*)(ws + pbytes);
  float*  s1  = (float*)(ws + 2 * pbytes);
  float*  e2  = (float*)(ws + 2 * pbytes + (size_t)B * N * sizeof(float));

  proj_mfma<<<(B * N) / 64, 256, 0, stream>>>(x, W1, b1, W2, b2, p1b, p2b, s1, e2);

  dim3 grid(N / 64, N / 128);
  fused_kernel<<<grid, 256, 0, stream>>>(p1b, p2b, s1, e2, out);
}